// Round 1
// baseline (566.633 us; speedup 1.0000x reference)
//
#include <hip/hip_runtime.h>
#include <hip/hip_bf16.h>

#define N_NODES 50000
#define N_EDGES 600000
#define FEA_DIM 128
#define H_DIM 256
#define N_LAYER 3
#define N_GRAPHS 256
#define LABEL_DIM 2

// ---------------- CSR build ----------------

__global__ __launch_bounds__(256) void k_init(int* __restrict__ counts, int* __restrict__ cursor) {
    int i = blockIdx.x * 256 + threadIdx.x;
    if (i < N_NODES) { counts[i] = 0; cursor[i] = 0; }
}

__global__ __launch_bounds__(256) void k_count(const int* __restrict__ dst, int* __restrict__ counts) {
    int e = blockIdx.x * 256 + threadIdx.x;
    if (e < N_EDGES) atomicAdd(&counts[dst[e]], 1);
}

// single-block exclusive scan of counts -> row_ptr, plus dinv = rsqrt(deg+1)
__global__ __launch_bounds__(1024) void k_scan(const int* __restrict__ counts,
                                               int* __restrict__ row_ptr,
                                               float* __restrict__ dinv) {
    __shared__ int part[1024];
    __shared__ int ex[1024];
    const int tid = threadIdx.x;
    const int CH = (N_NODES + 1023) / 1024;  // 49
    int start = tid * CH;
    int end = start + CH; if (end > N_NODES) end = N_NODES;
    int s = 0;
    for (int i = start; i < end; ++i) s += counts[i];
    part[tid] = s;
    __syncthreads();
    if (tid == 0) {
        int run = 0;
        for (int i = 0; i < 1024; ++i) { ex[i] = run; run += part[i]; }
        part[0] = run;  // grand total
    }
    __syncthreads();
    int run = ex[tid];
    for (int i = start; i < end; ++i) {
        row_ptr[i] = run;
        run += counts[i];
        dinv[i] = rsqrtf((float)counts[i] + 1.0f);  // +1 = self loop
    }
    if (tid == 0) row_ptr[N_NODES] = part[0];
}

__global__ __launch_bounds__(256) void k_fill(const int* __restrict__ src, const int* __restrict__ dst,
                                              const int* __restrict__ row_ptr, int* __restrict__ cursor,
                                              const float* __restrict__ dinv,
                                              int* __restrict__ col, float* __restrict__ wgt) {
    int e = blockIdx.x * 256 + threadIdx.x;
    if (e >= N_EDGES) return;
    int s = src[e], d = dst[e];
    int p = row_ptr[d] + atomicAdd(&cursor[d], 1);
    col[p] = s;
    wgt[p] = dinv[s] * dinv[d];
}

// ---------------- GEMM: H[M,128] = X[M,128] @ W[128,128] (fp32 vector) ----------------
// BM=64, BN=128, BK=64, 256 threads, 4x8 micro-tile per thread.

__global__ __launch_bounds__(256) void k_gemm(const float* __restrict__ X, const float* __restrict__ W,
                                              float* __restrict__ H, int M) {
    __shared__ float a_s[64][68];   // [k][m], +4 pad keeps 16B alignment
    __shared__ float b_s[64][128];  // [k][n]
    const int tid = threadIdx.x;
    const int row_g = tid >> 4;   // 0..15 -> 4 rows each
    const int col_g = tid & 15;   // 0..15 -> 8 cols each
    const int row_base = blockIdx.x * 64;
    float acc[4][8] = {};

    for (int kt = 0; kt < 2; ++kt) {
        const int k0 = kt * 64;
        // A tile: 64 rows x 64 k = 1024 float4
#pragma unroll
        for (int j = 0; j < 4; ++j) {
            int id = tid + j * 256;
            int m = id >> 4;
            int kq = (id & 15) << 2;
            float4 v = make_float4(0.f, 0.f, 0.f, 0.f);
            int gr = row_base + m;
            if (gr < M) v = *(const float4*)(X + gr * 128 + k0 + kq);
            a_s[kq + 0][m] = v.x; a_s[kq + 1][m] = v.y;
            a_s[kq + 2][m] = v.z; a_s[kq + 3][m] = v.w;
        }
        // B tile: 64 k x 128 n = 2048 float4
#pragma unroll
        for (int j = 0; j < 8; ++j) {
            int id = tid + j * 256;
            int k = id >> 5;
            int n = (id & 31) << 2;
            *(float4*)(&b_s[k][n]) = *(const float4*)(W + (k0 + k) * 128 + n);
        }
        __syncthreads();
#pragma unroll 16
        for (int k = 0; k < 64; ++k) {
            float4 a = *(const float4*)(&a_s[k][row_g * 4]);
            float4 b0 = *(const float4*)(&b_s[k][col_g * 8]);
            float4 b1 = *(const float4*)(&b_s[k][col_g * 8 + 4]);
            float av[4] = {a.x, a.y, a.z, a.w};
            float bv[8] = {b0.x, b0.y, b0.z, b0.w, b1.x, b1.y, b1.z, b1.w};
#pragma unroll
            for (int i = 0; i < 4; ++i)
#pragma unroll
                for (int jj = 0; jj < 8; ++jj) acc[i][jj] += av[i] * bv[jj];
        }
        __syncthreads();
    }
#pragma unroll
    for (int i = 0; i < 4; ++i) {
        int gr = row_base + row_g * 4 + i;
        if (gr < M) {
            float4 o0 = {acc[i][0], acc[i][1], acc[i][2], acc[i][3]};
            float4 o1 = {acc[i][4], acc[i][5], acc[i][6], acc[i][7]};
            *(float4*)(H + gr * 128 + col_g * 8) = o0;
            *(float4*)(H + gr * 128 + col_g * 8 + 4) = o1;
        }
    }
}

// ---------------- Aggregation: Xo[i] = relu(sum_{e:dst=i} w_e*H[src_e] + dinv[i]^2*H[i] + bg) ----
// one wave per node; lane covers features [2*lane, 2*lane+1] as float2

__global__ __launch_bounds__(256) void k_agg(const float* __restrict__ H, const float* __restrict__ bgl,
                                             const int* __restrict__ row_ptr, const int* __restrict__ col,
                                             const float* __restrict__ wgt, const float* __restrict__ dinv,
                                             float* __restrict__ Xo) {
    int wave = (blockIdx.x * 256 + threadIdx.x) >> 6;
    int lane = threadIdx.x & 63;
    if (wave >= N_NODES) return;
    const int i = wave;
    const float2* H2 = (const float2*)H;
    float di = dinv[i];
    float2 h = H2[i * 64 + lane];
    float2 acc;
    acc.x = h.x * di * di;
    acc.y = h.y * di * di;
    int p0 = row_ptr[i], p1 = row_ptr[i + 1];
    for (int base = p0; base < p1; base += 64) {
        int m = p1 - base; if (m > 64) m = 64;
        int sc = 0; float wc = 0.f;
        if (lane < m) { sc = col[base + lane]; wc = wgt[base + lane]; }
        for (int j = 0; j < m; ++j) {
            int s = __shfl(sc, j);
            float w = __shfl(wc, j);
            float2 hv = H2[s * 64 + lane];
            acc.x += hv.x * w;
            acc.y += hv.y * w;
        }
    }
    float2 b = ((const float2*)bgl)[lane];
    float2 o;
    o.x = fmaxf(acc.x + b.x, 0.f);
    o.y = fmaxf(acc.y + b.y, 0.f);
    ((float2*)Xo)[i * 64 + lane] = o;
}

// ---------------- Mean pool per graph (batch is sorted) ----------------

__global__ __launch_bounds__(256) void k_pool(const float* __restrict__ X, const int* __restrict__ batch,
                                              float* __restrict__ pooled) {
    __shared__ int s_lo, s_hi;
    __shared__ float red[256];
    int g = blockIdx.x, tid = threadIdx.x;
    if (tid == 0) {
        int lo = 0, hi = N_NODES;
        while (lo < hi) { int mid = (lo + hi) >> 1; if (batch[mid] < g) lo = mid + 1; else hi = mid; }
        s_lo = lo;
        int lo2 = lo, hi2 = N_NODES;
        while (lo2 < hi2) { int mid = (lo2 + hi2) >> 1; if (batch[mid] < g + 1) lo2 = mid + 1; else hi2 = mid; }
        s_hi = lo2;
    }
    __syncthreads();
    int lo = s_lo, hi = s_hi;
    int f = tid & 127, half = tid >> 7;
    float acc = 0.f;
    for (int r = lo + half; r < hi; r += 2) acc += X[r * 128 + f];
    red[tid] = acc;
    __syncthreads();
    if (tid < 128) {
        float t = red[tid] + red[tid + 128];
        int cnt = hi - lo;
        pooled[g * 128 + tid] = t / (float)(cnt > 0 ? cnt : 1);
    }
}

// ---------------- MLP head: out = relu(pooled@w1+b1)@w2+b2 ----------------

__global__ __launch_bounds__(256) void k_mlp(const float* __restrict__ pooled, const float* __restrict__ w1,
                                             const float* __restrict__ b1, const float* __restrict__ w2,
                                             const float* __restrict__ b2, float* __restrict__ out) {
    __shared__ float xs[128];
    __shared__ float hs[256];
    __shared__ float red[256];
    int g = blockIdx.x, tid = threadIdx.x;
    if (tid < 128) xs[tid] = pooled[g * 128 + tid];
    __syncthreads();
    float acc = b1[tid];
#pragma unroll 8
    for (int k = 0; k < 128; ++k) acc += xs[k] * w1[k * H_DIM + tid];
    hs[tid] = fmaxf(acc, 0.f);
    __syncthreads();
    int j = tid >> 7, t2 = tid & 127;
    float p = hs[t2] * w2[t2 * LABEL_DIM + j] + hs[t2 + 128] * w2[(t2 + 128) * LABEL_DIM + j];
    red[tid] = p;
    __syncthreads();
    for (int s2 = 64; s2 > 0; s2 >>= 1) {
        if (t2 < s2) red[tid] += red[tid + s2];
        __syncthreads();
    }
    if (t2 == 0) out[g * LABEL_DIM + j] = red[tid] + b2[j];
}

// ---------------- launch ----------------

extern "C" void kernel_launch(void* const* d_in, const int* in_sizes, int n_in,
                              void* d_out, int out_size, void* d_ws, size_t ws_size,
                              hipStream_t stream) {
    const float* x   = (const float*)d_in[0];
    const float* Wg  = (const float*)d_in[1];
    const float* bg  = (const float*)d_in[2];
    const float* w1  = (const float*)d_in[3];
    const float* b1  = (const float*)d_in[4];
    const float* w2  = (const float*)d_in[5];
    const float* b2  = (const float*)d_in[6];
    const int* eidx  = (const int*)d_in[7];
    const int* batch = (const int*)d_in[8];
    float* out = (float*)d_out;

    const int* src = eidx;
    const int* dst = eidx + N_EDGES;

    char* ws = (char*)d_ws;
    size_t off = 0;
    float* A = (float*)(ws + off); off += (size_t)N_NODES * FEA_DIM * 4;       // 25.6 MB
    float* B = (float*)(ws + off); off += (size_t)N_NODES * FEA_DIM * 4;       // 25.6 MB
    int*   col = (int*)(ws + off); off += (size_t)N_EDGES * 4;                 // 2.4 MB
    float* wgt = (float*)(ws + off); off += (size_t)N_EDGES * 4;               // 2.4 MB
    int*   row_ptr = (int*)(ws + off); off += 200192;
    int*   cursor  = (int*)(ws + off); off += 200192;
    int*   counts  = (int*)(ws + off); off += 200192;
    float* dinv    = (float*)(ws + off); off += 200192;
    float* pooled  = (float*)(ws + off); off += (size_t)N_GRAPHS * FEA_DIM * 4;

    k_init<<<(N_NODES + 255) / 256, 256, 0, stream>>>(counts, cursor);
    k_count<<<(N_EDGES + 255) / 256, 256, 0, stream>>>(dst, counts);
    k_scan<<<1, 1024, 0, stream>>>(counts, row_ptr, dinv);
    k_fill<<<(N_EDGES + 255) / 256, 256, 0, stream>>>(src, dst, row_ptr, cursor, dinv, col, wgt);

    const float* cur = x;
    for (int l = 0; l < N_LAYER; ++l) {
        k_gemm<<<(N_NODES + 63) / 64, 256, 0, stream>>>(cur, Wg + (size_t)l * FEA_DIM * FEA_DIM, B, N_NODES);
        k_agg<<<(N_NODES + 3) / 4, 256, 0, stream>>>(B, bg + (size_t)l * FEA_DIM, row_ptr, col, wgt, dinv, A);
        cur = A;
    }
    k_pool<<<N_GRAPHS, 256, 0, stream>>>(A, batch, pooled);
    k_mlp<<<N_GRAPHS, 256, 0, stream>>>(pooled, w1, b1, w2, b2, out);
}

// Round 2
// 460.075 us; speedup vs baseline: 1.2316x; 1.2316x over previous
//
#include <hip/hip_runtime.h>
#include <hip/hip_bf16.h>

#define N_NODES 50000
#define N_EDGES 600000
#define FEA_DIM 128
#define H_DIM 256
#define N_LAYER 3
#define N_GRAPHS 256
#define LABEL_DIM 2

#define SCAN_NB ((N_NODES + 255) / 256)   // 196

// ---------------- CSR build ----------------

__global__ __launch_bounds__(256) void k_init(int* __restrict__ counts, int* __restrict__ cursor) {
    int i = blockIdx.x * 256 + threadIdx.x;
    if (i < N_NODES) { counts[i] = 0; cursor[i] = 0; }
}

__global__ __launch_bounds__(256) void k_count(const int* __restrict__ dst, int* __restrict__ counts) {
    int e = blockIdx.x * 256 + threadIdx.x;
    if (e < N_EDGES) atomicAdd(&counts[dst[e]], 1);
}

// Phase 1: per-block (256-chunk) sum of counts -> partial[blockIdx]
__global__ __launch_bounds__(256) void k_partial(const int* __restrict__ counts, int* __restrict__ partial) {
    int g = blockIdx.x * 256 + threadIdx.x;
    int v = (g < N_NODES) ? counts[g] : 0;
#pragma unroll
    for (int off = 32; off > 0; off >>= 1) v += __shfl_down(v, off);
    __shared__ int ws[4];
    int lane = threadIdx.x & 63, wid = threadIdx.x >> 6;
    if (lane == 0) ws[wid] = v;
    __syncthreads();
    if (threadIdx.x == 0) partial[blockIdx.x] = ws[0] + ws[1] + ws[2] + ws[3];
}

// Phase 2: single small block scans the 196 partials -> exclusive offsets + total
__global__ __launch_bounds__(256) void k_scanpart(int* __restrict__ partial, int* __restrict__ row_ptr) {
    __shared__ int s[256];
    int tid = threadIdx.x;
    int v = (tid < SCAN_NB) ? partial[tid] : 0;
    s[tid] = v;
    __syncthreads();
#pragma unroll
    for (int off = 1; off < 256; off <<= 1) {
        int t = (tid >= off) ? s[tid - off] : 0;
        __syncthreads();
        s[tid] += t;
        __syncthreads();
    }
    // exclusive offset for block tid
    if (tid < SCAN_NB) partial[tid] = (tid == 0) ? 0 : s[tid - 1];
    if (tid == 0) row_ptr[N_NODES] = s[SCAN_NB - 1];
}

// Phase 3: block-local exclusive scan + block offset -> row_ptr; also dinv
__global__ __launch_bounds__(256) void k_rowptr(const int* __restrict__ counts, const int* __restrict__ partial,
                                                int* __restrict__ row_ptr, float* __restrict__ dinv) {
    __shared__ int s[256];
    int tid = threadIdx.x;
    int g = blockIdx.x * 256 + tid;
    int c = (g < N_NODES) ? counts[g] : 0;
    s[tid] = c;
    __syncthreads();
#pragma unroll
    for (int off = 1; off < 256; off <<= 1) {
        int t = (tid >= off) ? s[tid - off] : 0;
        __syncthreads();
        s[tid] += t;
        __syncthreads();
    }
    if (g < N_NODES) {
        row_ptr[g] = partial[blockIdx.x] + s[tid] - c;  // exclusive
        dinv[g] = rsqrtf((float)c + 1.0f);              // +1 = self loop
    }
}

__global__ __launch_bounds__(256) void k_fill(const int* __restrict__ src, const int* __restrict__ dst,
                                              const int* __restrict__ row_ptr, int* __restrict__ cursor,
                                              const float* __restrict__ dinv,
                                              int* __restrict__ col, float* __restrict__ wgt) {
    int e = blockIdx.x * 256 + threadIdx.x;
    if (e >= N_EDGES) return;
    int s = src[e], d = dst[e];
    int p = row_ptr[d] + atomicAdd(&cursor[d], 1);
    col[p] = s;
    wgt[p] = dinv[s] * dinv[d];
}

// ---------------- GEMM: H[M,128] = X[M,128] @ W[128,128] (fp32 vector) ----------------
// BM=64, BN=128, BK=64, 256 threads, 4x8 micro-tile per thread.

__global__ __launch_bounds__(256) void k_gemm(const float* __restrict__ X, const float* __restrict__ W,
                                              float* __restrict__ H, int M) {
    __shared__ float a_s[64][68];   // [k][m], +4 pad keeps 16B alignment
    __shared__ float b_s[64][128];  // [k][n]
    const int tid = threadIdx.x;
    const int row_g = tid >> 4;   // 0..15 -> 4 rows each
    const int col_g = tid & 15;   // 0..15 -> 8 cols each
    const int row_base = blockIdx.x * 64;
    float acc[4][8] = {};

    for (int kt = 0; kt < 2; ++kt) {
        const int k0 = kt * 64;
#pragma unroll
        for (int j = 0; j < 4; ++j) {
            int id = tid + j * 256;
            int m = id >> 4;
            int kq = (id & 15) << 2;
            float4 v = make_float4(0.f, 0.f, 0.f, 0.f);
            int gr = row_base + m;
            if (gr < M) v = *(const float4*)(X + gr * 128 + k0 + kq);
            a_s[kq + 0][m] = v.x; a_s[kq + 1][m] = v.y;
            a_s[kq + 2][m] = v.z; a_s[kq + 3][m] = v.w;
        }
#pragma unroll
        for (int j = 0; j < 8; ++j) {
            int id = tid + j * 256;
            int k = id >> 5;
            int n = (id & 31) << 2;
            *(float4*)(&b_s[k][n]) = *(const float4*)(W + (k0 + k) * 128 + n);
        }
        __syncthreads();
#pragma unroll 16
        for (int k = 0; k < 64; ++k) {
            float4 a = *(const float4*)(&a_s[k][row_g * 4]);
            float4 b0 = *(const float4*)(&b_s[k][col_g * 8]);
            float4 b1 = *(const float4*)(&b_s[k][col_g * 8 + 4]);
            float av[4] = {a.x, a.y, a.z, a.w};
            float bv[8] = {b0.x, b0.y, b0.z, b0.w, b1.x, b1.y, b1.z, b1.w};
#pragma unroll
            for (int i = 0; i < 4; ++i)
#pragma unroll
                for (int jj = 0; jj < 8; ++jj) acc[i][jj] += av[i] * bv[jj];
        }
        __syncthreads();
    }
#pragma unroll
    for (int i = 0; i < 4; ++i) {
        int gr = row_base + row_g * 4 + i;
        if (gr < M) {
            float4 o0 = {acc[i][0], acc[i][1], acc[i][2], acc[i][3]};
            float4 o1 = {acc[i][4], acc[i][5], acc[i][6], acc[i][7]};
            *(float4*)(H + gr * 128 + col_g * 8) = o0;
            *(float4*)(H + gr * 128 + col_g * 8 + 4) = o1;
        }
    }
}

// ---------------- Aggregation ----------------
// one wave per node; lane covers features [2*lane, 2*lane+1] as float2

__global__ __launch_bounds__(256) void k_agg(const float* __restrict__ H, const float* __restrict__ bgl,
                                             const int* __restrict__ row_ptr, const int* __restrict__ col,
                                             const float* __restrict__ wgt, const float* __restrict__ dinv,
                                             float* __restrict__ Xo) {
    int wave = (blockIdx.x * 256 + threadIdx.x) >> 6;
    int lane = threadIdx.x & 63;
    if (wave >= N_NODES) return;
    const int i = wave;
    const float2* H2 = (const float2*)H;
    float di = dinv[i];
    float2 h = H2[i * 64 + lane];
    float2 acc;
    acc.x = h.x * di * di;
    acc.y = h.y * di * di;
    int p0 = row_ptr[i], p1 = row_ptr[i + 1];
    for (int base = p0; base < p1; base += 64) {
        int m = p1 - base; if (m > 64) m = 64;
        int sc = 0; float wc = 0.f;
        if (lane < m) { sc = col[base + lane]; wc = wgt[base + lane]; }
        for (int j = 0; j < m; ++j) {
            int s = __shfl(sc, j);
            float w = __shfl(wc, j);
            float2 hv = H2[s * 64 + lane];
            acc.x += hv.x * w;
            acc.y += hv.y * w;
        }
    }
    float2 b = ((const float2*)bgl)[lane];
    float2 o;
    o.x = fmaxf(acc.x + b.x, 0.f);
    o.y = fmaxf(acc.y + b.y, 0.f);
    ((float2*)Xo)[i * 64 + lane] = o;
}

// ---------------- Mean pool per graph (batch is sorted) ----------------

__global__ __launch_bounds__(256) void k_pool(const float* __restrict__ X, const int* __restrict__ batch,
                                              float* __restrict__ pooled) {
    __shared__ int s_lo, s_hi;
    __shared__ float red[256];
    int g = blockIdx.x, tid = threadIdx.x;
    if (tid == 0) {
        int lo = 0, hi = N_NODES;
        while (lo < hi) { int mid = (lo + hi) >> 1; if (batch[mid] < g) lo = mid + 1; else hi = mid; }
        s_lo = lo;
        int lo2 = lo, hi2 = N_NODES;
        while (lo2 < hi2) { int mid = (lo2 + hi2) >> 1; if (batch[mid] < g + 1) lo2 = mid + 1; else hi2 = mid; }
        s_hi = lo2;
    }
    __syncthreads();
    int lo = s_lo, hi = s_hi;
    int f = tid & 127, half = tid >> 7;
    float acc = 0.f;
    for (int r = lo + half; r < hi; r += 2) acc += X[r * 128 + f];
    red[tid] = acc;
    __syncthreads();
    if (tid < 128) {
        float t = red[tid] + red[tid + 128];
        int cnt = hi - lo;
        pooled[g * 128 + tid] = t / (float)(cnt > 0 ? cnt : 1);
    }
}

// ---------------- MLP head ----------------

__global__ __launch_bounds__(256) void k_mlp(const float* __restrict__ pooled, const float* __restrict__ w1,
                                             const float* __restrict__ b1, const float* __restrict__ w2,
                                             const float* __restrict__ b2, float* __restrict__ out) {
    __shared__ float xs[128];
    __shared__ float hs[256];
    __shared__ float red[256];
    int g = blockIdx.x, tid = threadIdx.x;
    if (tid < 128) xs[tid] = pooled[g * 128 + tid];
    __syncthreads();
    float acc = b1[tid];
#pragma unroll 8
    for (int k = 0; k < 128; ++k) acc += xs[k] * w1[k * H_DIM + tid];
    hs[tid] = fmaxf(acc, 0.f);
    __syncthreads();
    int j = tid >> 7, t2 = tid & 127;
    float p = hs[t2] * w2[t2 * LABEL_DIM + j] + hs[t2 + 128] * w2[(t2 + 128) * LABEL_DIM + j];
    red[tid] = p;
    __syncthreads();
    for (int s2 = 64; s2 > 0; s2 >>= 1) {
        if (t2 < s2) red[tid] += red[tid + s2];
        __syncthreads();
    }
    if (t2 == 0) out[g * LABEL_DIM + j] = red[tid] + b2[j];
}

// ---------------- launch ----------------

extern "C" void kernel_launch(void* const* d_in, const int* in_sizes, int n_in,
                              void* d_out, int out_size, void* d_ws, size_t ws_size,
                              hipStream_t stream) {
    const float* x   = (const float*)d_in[0];
    const float* Wg  = (const float*)d_in[1];
    const float* bg  = (const float*)d_in[2];
    const float* w1  = (const float*)d_in[3];
    const float* b1  = (const float*)d_in[4];
    const float* w2  = (const float*)d_in[5];
    const float* b2  = (const float*)d_in[6];
    const int* eidx  = (const int*)d_in[7];
    const int* batch = (const int*)d_in[8];
    float* out = (float*)d_out;

    const int* src = eidx;
    const int* dst = eidx + N_EDGES;

    char* ws = (char*)d_ws;
    size_t off = 0;
    float* A = (float*)(ws + off); off += (size_t)N_NODES * FEA_DIM * 4;       // 25.6 MB
    float* B = (float*)(ws + off); off += (size_t)N_NODES * FEA_DIM * 4;       // 25.6 MB
    int*   col = (int*)(ws + off); off += (size_t)N_EDGES * 4;                 // 2.4 MB
    float* wgt = (float*)(ws + off); off += (size_t)N_EDGES * 4;               // 2.4 MB
    int*   row_ptr = (int*)(ws + off); off += 200704;
    int*   cursor  = (int*)(ws + off); off += 200704;
    int*   counts  = (int*)(ws + off); off += 200704;
    float* dinv    = (float*)(ws + off); off += 200704;
    int*   partial = (int*)(ws + off); off += 4096;
    float* pooled  = (float*)(ws + off); off += (size_t)N_GRAPHS * FEA_DIM * 4;

    k_init<<<(N_NODES + 255) / 256, 256, 0, stream>>>(counts, cursor);
    k_count<<<(N_EDGES + 255) / 256, 256, 0, stream>>>(dst, counts);
    k_partial<<<SCAN_NB, 256, 0, stream>>>(counts, partial);
    k_scanpart<<<1, 256, 0, stream>>>(partial, row_ptr);
    k_rowptr<<<SCAN_NB, 256, 0, stream>>>(counts, partial, row_ptr, dinv);
    k_fill<<<(N_EDGES + 255) / 256, 256, 0, stream>>>(src, dst, row_ptr, cursor, dinv, col, wgt);

    const float* cur = x;
    for (int l = 0; l < N_LAYER; ++l) {
        k_gemm<<<(N_NODES + 63) / 64, 256, 0, stream>>>(cur, Wg + (size_t)l * FEA_DIM * FEA_DIM, B, N_NODES);
        k_agg<<<(N_NODES + 3) / 4, 256, 0, stream>>>(B, bg + (size_t)l * FEA_DIM, row_ptr, col, wgt, dinv, A);
        cur = A;
    }
    k_pool<<<N_GRAPHS, 256, 0, stream>>>(A, batch, pooled);
    k_mlp<<<N_GRAPHS, 256, 0, stream>>>(pooled, w1, b1, w2, b2, out);
}

// Round 4
// 422.535 us; speedup vs baseline: 1.3410x; 1.0888x over previous
//
#include <hip/hip_runtime.h>
#include <hip/hip_bf16.h>

#define N_NODES 50000
#define N_EDGES 600000
#define FEA_DIM 128
#define H_DIM 256
#define N_LAYER 3
#define N_GRAPHS 256
#define LABEL_DIM 2

#define SCAN_NB ((N_NODES + 255) / 256)   // 196

// ---------------- CSR build ----------------

__global__ __launch_bounds__(256) void k_count(const int* __restrict__ dst, int* __restrict__ counts) {
    int e = blockIdx.x * 256 + threadIdx.x;
    if (e < N_EDGES) atomicAdd(&counts[dst[e]], 1);
}

// per-block (256-chunk) sum of counts -> partial[blockIdx]
__global__ __launch_bounds__(256) void k_partial(const int* __restrict__ counts, int* __restrict__ partial) {
    int g = blockIdx.x * 256 + threadIdx.x;
    int v = (g < N_NODES) ? counts[g] : 0;
#pragma unroll
    for (int off = 32; off > 0; off >>= 1) v += __shfl_down(v, off);
    __shared__ int ws[4];
    int lane = threadIdx.x & 63, wid = threadIdx.x >> 6;
    if (lane == 0) ws[wid] = v;
    __syncthreads();
    if (threadIdx.x == 0) partial[blockIdx.x] = ws[0] + ws[1] + ws[2] + ws[3];
}

// each block redundantly scans the 196 partials in LDS, then block-local scan of counts.
__global__ __launch_bounds__(256) void k_rowptr(const int* __restrict__ counts, const int* __restrict__ partial,
                                                int* __restrict__ row_ptr, float* __restrict__ dinv) {
    __shared__ int sp[256];
    __shared__ int s[256];
    int tid = threadIdx.x;
    sp[tid] = (tid < SCAN_NB) ? partial[tid] : 0;
    __syncthreads();
#pragma unroll
    for (int off = 1; off < 256; off <<= 1) {
        int t = (tid >= off) ? sp[tid - off] : 0;
        __syncthreads();
        sp[tid] += t;
        __syncthreads();
    }
    int block_off = (blockIdx.x == 0) ? 0 : sp[blockIdx.x - 1];

    int g = blockIdx.x * 256 + tid;
    int c = (g < N_NODES) ? counts[g] : 0;
    s[tid] = c;
    __syncthreads();
#pragma unroll
    for (int off = 1; off < 256; off <<= 1) {
        int t = (tid >= off) ? s[tid - off] : 0;
        __syncthreads();
        s[tid] += t;
        __syncthreads();
    }
    if (g < N_NODES) {
        row_ptr[g] = block_off + s[tid] - c;            // exclusive
        dinv[g] = rsqrtf((float)c + 1.0f);              // +1 = self loop
    }
    if (blockIdx.x == 0 && tid == 0) row_ptr[N_NODES] = sp[SCAN_NB - 1];
}

__global__ __launch_bounds__(256) void k_fill(const int* __restrict__ src, const int* __restrict__ dst,
                                              const int* __restrict__ row_ptr, int* __restrict__ cursor,
                                              int* __restrict__ col) {
    int e = blockIdx.x * 256 + threadIdx.x;
    if (e >= N_EDGES) return;
    int s = src[e], d = dst[e];
    int p = row_ptr[d] + atomicAdd(&cursor[d], 1);
    col[p] = s;
}

// ---------------- GEMM: H[M,128] = X[M,128] @ W[128,128] (fp32 vector) ----------------
// BM=128, BN=128, BK=32, 256 threads, 8x8 micro-tile; A staged transposed [k][m].
// k accumulation order is ascending 0..127 — bitwise identical to the round-2 kernel.

__global__ __launch_bounds__(256) void k_gemm(const float* __restrict__ X, const float* __restrict__ W,
                                              float* __restrict__ H, int M) {
    __shared__ float a_s[32][132];   // [k][m], pad 132
    __shared__ float b_s[32][128];   // [k][n]
    const int tid = threadIdx.x;
    const int row_g = tid >> 4;   // 0..15 -> 8 rows each
    const int col_g = tid & 15;   // 0..15 -> cols col_g*4 and 64+col_g*4
    const int row_base = blockIdx.x * 128;
    float acc[8][8] = {};

    for (int kt = 0; kt < 4; ++kt) {
        const int k0 = kt * 32;
#pragma unroll
        for (int j = 0; j < 4; ++j) {
            int id = tid + j * 256;
            int m = id >> 3;
            int kq = (id & 7) << 2;
            float4 v = make_float4(0.f, 0.f, 0.f, 0.f);
            int gr = row_base + m;
            if (gr < M) v = *(const float4*)(X + gr * 128 + k0 + kq);
            a_s[kq + 0][m] = v.x; a_s[kq + 1][m] = v.y;
            a_s[kq + 2][m] = v.z; a_s[kq + 3][m] = v.w;
        }
#pragma unroll
        for (int j = 0; j < 4; ++j) {
            int id = tid + j * 256;
            int k = id >> 5;
            int n = (id & 31) << 2;
            *(float4*)(&b_s[k][n]) = *(const float4*)(W + (k0 + k) * 128 + n);
        }
        __syncthreads();
#pragma unroll 8
        for (int k = 0; k < 32; ++k) {
            float4 a0 = *(const float4*)(&a_s[k][row_g * 8]);
            float4 a1 = *(const float4*)(&a_s[k][row_g * 8 + 4]);
            float4 b0 = *(const float4*)(&b_s[k][col_g * 4]);
            float4 b1 = *(const float4*)(&b_s[k][64 + col_g * 4]);
            float av[8] = {a0.x, a0.y, a0.z, a0.w, a1.x, a1.y, a1.z, a1.w};
            float bv[8] = {b0.x, b0.y, b0.z, b0.w, b1.x, b1.y, b1.z, b1.w};
#pragma unroll
            for (int i = 0; i < 8; ++i)
#pragma unroll
                for (int jj = 0; jj < 8; ++jj) acc[i][jj] += av[i] * bv[jj];
        }
        __syncthreads();
    }
#pragma unroll
    for (int i = 0; i < 8; ++i) {
        int gr = row_base + row_g * 8 + i;
        if (gr < M) {
            float4 o0 = {acc[i][0], acc[i][1], acc[i][2], acc[i][3]};
            float4 o1 = {acc[i][4], acc[i][5], acc[i][6], acc[i][7]};
            *(float4*)(H + gr * 128 + col_g * 4) = o0;
            *(float4*)(H + gr * 128 + 64 + col_g * 4) = o1;
        }
    }
}

// ---------------- Aggregation ----------------
// one wave per node, lane covers feats [2*lane, 2*lane+1] as float2.
// ACCUMULATION ORDER: self-loop first, then CSR edges strictly ascending —
// bitwise identical to the round-2 kernel (absmax 0.0). Memory-level
// parallelism comes from batch-of-8 prefetch: issue 8 independent gathers,
// THEN accumulate them in order.

__global__ __launch_bounds__(256) void k_agg(const float* __restrict__ H, const float* __restrict__ bgl,
                                             const int* __restrict__ row_ptr, const int* __restrict__ col,
                                             const float* __restrict__ dinv,
                                             float* __restrict__ Xo) {
    int wave = (blockIdx.x * 256 + threadIdx.x) >> 6;
    int lane = threadIdx.x & 63;
    if (wave >= N_NODES) return;
    const int i = wave;
    const float2* H2 = (const float2*)H;
    const float di = dinv[i];
    float2 h = H2[i * 64 + lane];
    float2 acc;
    acc.x = h.x * di * di;   // self-loop first (round-2 order)
    acc.y = h.y * di * di;
    const int p0 = row_ptr[i], p1 = row_ptr[i + 1];
    for (int base = p0; base < p1; base += 64) {
        int m = p1 - base; if (m > 64) m = 64;
        int sc = 0; float wc = 0.f;
        if (lane < m) { sc = col[base + lane]; wc = dinv[sc] * di; }
        for (int j = 0; j < m; j += 8) {
            int cnt = m - j; if (cnt > 8) cnt = 8;
            float2 hbuf[8]; float wbuf[8];
            // phase 1: issue all gathers (independent loads, 8 in flight)
#pragma unroll
            for (int t = 0; t < 8; ++t) {
                if (t < cnt) {
                    int s = __shfl(sc, j + t);
                    wbuf[t] = __shfl(wc, j + t);
                    hbuf[t] = H2[s * 64 + lane];
                }
            }
            // phase 2: accumulate strictly in ascending edge order
#pragma unroll
            for (int t = 0; t < 8; ++t) {
                if (t < cnt) {
                    acc.x += hbuf[t].x * wbuf[t];
                    acc.y += hbuf[t].y * wbuf[t];
                }
            }
        }
    }
    float2 b = ((const float2*)bgl)[lane];
    float2 o;
    o.x = fmaxf(acc.x + b.x, 0.f);
    o.y = fmaxf(acc.y + b.y, 0.f);
    ((float2*)Xo)[i * 64 + lane] = o;
}

// ---------------- Fused mean pool + MLP head ----------------

__global__ __launch_bounds__(256) void k_poolmlp(const float* __restrict__ X, const int* __restrict__ batch,
                                                 const float* __restrict__ w1, const float* __restrict__ b1,
                                                 const float* __restrict__ w2, const float* __restrict__ b2,
                                                 float* __restrict__ out) {
    __shared__ int s_lo, s_hi;
    __shared__ float red[256];
    __shared__ float xs[128];
    __shared__ float hs[256];
    int g = blockIdx.x, tid = threadIdx.x;
    if (tid == 0) {
        int lo = 0, hi = N_NODES;
        while (lo < hi) { int mid = (lo + hi) >> 1; if (batch[mid] < g) lo = mid + 1; else hi = mid; }
        s_lo = lo;
        int lo2 = lo, hi2 = N_NODES;
        while (lo2 < hi2) { int mid = (lo2 + hi2) >> 1; if (batch[mid] < g + 1) lo2 = mid + 1; else hi2 = mid; }
        s_hi = lo2;
    }
    __syncthreads();
    int lo = s_lo, hi = s_hi;
    int f = tid & 127, half = tid >> 7;
    float acc = 0.f;
    for (int r = lo + half; r < hi; r += 2) acc += X[r * 128 + f];
    red[tid] = acc;
    __syncthreads();
    if (tid < 128) {
        int cnt = hi - lo;
        xs[tid] = (red[tid] + red[tid + 128]) / (float)(cnt > 0 ? cnt : 1);
    }
    __syncthreads();
    float a1 = b1[tid];
#pragma unroll 8
    for (int k = 0; k < 128; ++k) a1 += xs[k] * w1[k * H_DIM + tid];
    hs[tid] = fmaxf(a1, 0.f);
    __syncthreads();
    int j = tid >> 7, t2 = tid & 127;
    float p = hs[t2] * w2[t2 * LABEL_DIM + j] + hs[t2 + 128] * w2[(t2 + 128) * LABEL_DIM + j];
    red[tid] = p;
    __syncthreads();
    for (int s2 = 64; s2 > 0; s2 >>= 1) {
        if (t2 < s2) red[tid] += red[tid + s2];
        __syncthreads();
    }
    if (t2 == 0) out[g * LABEL_DIM + j] = red[tid] + b2[j];
}

// ---------------- launch ----------------

extern "C" void kernel_launch(void* const* d_in, const int* in_sizes, int n_in,
                              void* d_out, int out_size, void* d_ws, size_t ws_size,
                              hipStream_t stream) {
    const float* x   = (const float*)d_in[0];
    const float* Wg  = (const float*)d_in[1];
    const float* bg  = (const float*)d_in[2];
    const float* w1  = (const float*)d_in[3];
    const float* b1  = (const float*)d_in[4];
    const float* w2  = (const float*)d_in[5];
    const float* b2  = (const float*)d_in[6];
    const int* eidx  = (const int*)d_in[7];
    const int* batch = (const int*)d_in[8];
    float* out = (float*)d_out;

    const int* src = eidx;
    const int* dst = eidx + N_EDGES;

    char* ws = (char*)d_ws;
    size_t off = 0;
    float* A = (float*)(ws + off); off += (size_t)N_NODES * FEA_DIM * 4;       // 25.6 MB
    float* B = (float*)(ws + off); off += (size_t)N_NODES * FEA_DIM * 4;       // 25.6 MB
    int*   col = (int*)(ws + off); off += (size_t)N_EDGES * 4;                 // 2.4 MB
    int*   row_ptr = (int*)(ws + off); off += 200704;
    int*   cursor  = (int*)(ws + off); off += 200704;                          // adjacent:
    int*   counts  = (int*)(ws + off); off += 200704;                          //  one memset
    float* dinv    = (float*)(ws + off); off += 200704;
    int*   partial = (int*)(ws + off); off += 4096;

    hipMemsetAsync(cursor, 0, 2 * 200704, stream);   // zeros cursor + counts
    k_count<<<(N_EDGES + 255) / 256, 256, 0, stream>>>(dst, counts);
    k_partial<<<SCAN_NB, 256, 0, stream>>>(counts, partial);
    k_rowptr<<<SCAN_NB, 256, 0, stream>>>(counts, partial, row_ptr, dinv);
    k_fill<<<(N_EDGES + 255) / 256, 256, 0, stream>>>(src, dst, row_ptr, cursor, col);

    const float* cur = x;
    for (int l = 0; l < N_LAYER; ++l) {
        k_gemm<<<(N_NODES + 127) / 128, 256, 0, stream>>>(cur, Wg + (size_t)l * FEA_DIM * FEA_DIM, B, N_NODES);
        k_agg<<<(N_NODES + 3) / 4, 256, 0, stream>>>(B, bg + (size_t)l * FEA_DIM, row_ptr, col, dinv, A);
        cur = A;
    }
    k_poolmlp<<<N_GRAPHS, 256, 0, stream>>>(A, batch, w1, b1, w2, b2, out);
}

// Round 5
// 420.458 us; speedup vs baseline: 1.3477x; 1.0049x over previous
//
#include <hip/hip_runtime.h>
#include <hip/hip_bf16.h>

#define N_NODES 50000
#define N_EDGES 600000
#define FEA_DIM 128
#define H_DIM 256
#define N_LAYER 3
#define N_GRAPHS 256
#define LABEL_DIM 2

#define SCAN_NB ((N_NODES + 255) / 256)   // 196

// ---------------- CSR build ----------------

__global__ __launch_bounds__(256) void k_count(const int* __restrict__ dst, int* __restrict__ counts) {
    int e = blockIdx.x * 256 + threadIdx.x;
    if (e < N_EDGES) atomicAdd(&counts[dst[e]], 1);
}

__global__ __launch_bounds__(256) void k_partial(const int* __restrict__ counts, int* __restrict__ partial) {
    int g = blockIdx.x * 256 + threadIdx.x;
    int v = (g < N_NODES) ? counts[g] : 0;
#pragma unroll
    for (int off = 32; off > 0; off >>= 1) v += __shfl_down(v, off);
    __shared__ int ws[4];
    int lane = threadIdx.x & 63, wid = threadIdx.x >> 6;
    if (lane == 0) ws[wid] = v;
    __syncthreads();
    if (threadIdx.x == 0) partial[blockIdx.x] = ws[0] + ws[1] + ws[2] + ws[3];
}

__global__ __launch_bounds__(256) void k_rowptr(const int* __restrict__ counts, const int* __restrict__ partial,
                                                int* __restrict__ row_ptr, float* __restrict__ dinv) {
    __shared__ int sp[256];
    __shared__ int s[256];
    int tid = threadIdx.x;
    sp[tid] = (tid < SCAN_NB) ? partial[tid] : 0;
    __syncthreads();
#pragma unroll
    for (int off = 1; off < 256; off <<= 1) {
        int t = (tid >= off) ? sp[tid - off] : 0;
        __syncthreads();
        sp[tid] += t;
        __syncthreads();
    }
    int block_off = (blockIdx.x == 0) ? 0 : sp[blockIdx.x - 1];

    int g = blockIdx.x * 256 + tid;
    int c = (g < N_NODES) ? counts[g] : 0;
    s[tid] = c;
    __syncthreads();
#pragma unroll
    for (int off = 1; off < 256; off <<= 1) {
        int t = (tid >= off) ? s[tid - off] : 0;
        __syncthreads();
        s[tid] += t;
        __syncthreads();
    }
    if (g < N_NODES) {
        row_ptr[g] = block_off + s[tid] - c;            // exclusive
        dinv[g] = rsqrtf((float)c + 1.0f);              // +1 = self loop
    }
    if (blockIdx.x == 0 && tid == 0) row_ptr[N_NODES] = sp[SCAN_NB - 1];
}

__global__ __launch_bounds__(256) void k_fill(const int* __restrict__ src, const int* __restrict__ dst,
                                              const int* __restrict__ row_ptr, int* __restrict__ cursor,
                                              int* __restrict__ col) {
    int e = blockIdx.x * 256 + threadIdx.x;
    if (e >= N_EDGES) return;
    int s = src[e], d = dst[e];
    int p = row_ptr[d] + atomicAdd(&cursor[d], 1);
    col[p] = s;
}

// ---------------- GEMM: H[M,128] = X[M,128] @ W[128,128] (fp32 vector) ----------------
// BM=128, BN=128, BK=32, 256 threads, 8x8 micro-tile; A staged transposed [k][m].
// k accumulation order ascending 0..127 — bitwise stable across rounds.

__global__ __launch_bounds__(256) void k_gemm(const float* __restrict__ X, const float* __restrict__ W,
                                              float* __restrict__ H, int M) {
    __shared__ float a_s[32][132];
    __shared__ float b_s[32][128];
    const int tid = threadIdx.x;
    const int row_g = tid >> 4;
    const int col_g = tid & 15;
    const int row_base = blockIdx.x * 128;
    float acc[8][8] = {};

    for (int kt = 0; kt < 4; ++kt) {
        const int k0 = kt * 32;
#pragma unroll
        for (int j = 0; j < 4; ++j) {
            int id = tid + j * 256;
            int m = id >> 3;
            int kq = (id & 7) << 2;
            float4 v = make_float4(0.f, 0.f, 0.f, 0.f);
            int gr = row_base + m;
            if (gr < M) v = *(const float4*)(X + gr * 128 + k0 + kq);
            a_s[kq + 0][m] = v.x; a_s[kq + 1][m] = v.y;
            a_s[kq + 2][m] = v.z; a_s[kq + 3][m] = v.w;
        }
#pragma unroll
        for (int j = 0; j < 4; ++j) {
            int id = tid + j * 256;
            int k = id >> 5;
            int n = (id & 31) << 2;
            *(float4*)(&b_s[k][n]) = *(const float4*)(W + (k0 + k) * 128 + n);
        }
        __syncthreads();
#pragma unroll 8
        for (int k = 0; k < 32; ++k) {
            float4 a0 = *(const float4*)(&a_s[k][row_g * 8]);
            float4 a1 = *(const float4*)(&a_s[k][row_g * 8 + 4]);
            float4 b0 = *(const float4*)(&b_s[k][col_g * 4]);
            float4 b1 = *(const float4*)(&b_s[k][64 + col_g * 4]);
            float av[8] = {a0.x, a0.y, a0.z, a0.w, a1.x, a1.y, a1.z, a1.w};
            float bv[8] = {b0.x, b0.y, b0.z, b0.w, b1.x, b1.y, b1.z, b1.w};
#pragma unroll
            for (int i = 0; i < 8; ++i)
#pragma unroll
                for (int jj = 0; jj < 8; ++jj) acc[i][jj] += av[i] * bv[jj];
        }
        __syncthreads();
    }
#pragma unroll
    for (int i = 0; i < 8; ++i) {
        int gr = row_base + row_g * 8 + i;
        if (gr < M) {
            float4 o0 = {acc[i][0], acc[i][1], acc[i][2], acc[i][3]};
            float4 o1 = {acc[i][4], acc[i][5], acc[i][6], acc[i][7]};
            *(float4*)(H + gr * 128 + col_g * 4) = o0;
            *(float4*)(H + gr * 128 + 64 + col_g * 4) = o1;
        }
    }
}

// ---------------- Aggregation v3 ----------------
// TWO nodes per wave: lanes 0-31 -> node 2w, lanes 32-63 -> node 2w+1.
// Each lane holds 4 feats (float4). Per half-wave: self-loop first, then CSR
// edges strictly ascending with 8-deep gather prefetch. Per output element the
// fmac order is identical to round 4 (absmax 0.0) — only the lane->feature
// partitioning changed.

__global__ __launch_bounds__(256) void k_agg(const float* __restrict__ H, const float* __restrict__ bgl,
                                             const int* __restrict__ row_ptr, const int* __restrict__ col,
                                             const float* __restrict__ dinv,
                                             float* __restrict__ Xo) {
    const int i = (blockIdx.x * 256 + threadIdx.x) >> 5;   // node id, one per half-wave
    if (i >= N_NODES) return;
    const int fl = threadIdx.x & 31;                       // float4 index within node
    const float4* H4 = (const float4*)H;
    const float di = dinv[i];
    float4 h = H4[i * 32 + fl];
    float4 acc;
    const float wself = di * di;
    acc.x = h.x * wself; acc.y = h.y * wself; acc.z = h.z * wself; acc.w = h.w * wself;
    const int p0 = row_ptr[i], p1 = row_ptr[i + 1];
    for (int base = p0; base < p1; base += 32) {
        int m = p1 - base; if (m > 32) m = 32;
        int sc = 0; float wc = 0.f;
        if (fl < m) { sc = col[base + fl]; wc = dinv[sc] * di; }
        for (int j = 0; j < m; j += 8) {
            int cnt = m - j; if (cnt > 8) cnt = 8;
            float4 hbuf[8]; float wbuf[8];
            // phase 1: issue independent gathers (8 in flight per half-wave)
#pragma unroll
            for (int t = 0; t < 8; ++t) {
                if (t < cnt) {
                    int s = __shfl(sc, j + t, 32);
                    wbuf[t] = __shfl(wc, j + t, 32);
                    hbuf[t] = H4[(size_t)s * 32 + fl];
                }
            }
            // phase 2: accumulate strictly in ascending edge order
#pragma unroll
            for (int t = 0; t < 8; ++t) {
                if (t < cnt) {
                    acc.x += hbuf[t].x * wbuf[t];
                    acc.y += hbuf[t].y * wbuf[t];
                    acc.z += hbuf[t].z * wbuf[t];
                    acc.w += hbuf[t].w * wbuf[t];
                }
            }
        }
    }
    float4 b = ((const float4*)bgl)[fl];
    float4 o;
    o.x = fmaxf(acc.x + b.x, 0.f);
    o.y = fmaxf(acc.y + b.y, 0.f);
    o.z = fmaxf(acc.z + b.z, 0.f);
    o.w = fmaxf(acc.w + b.w, 0.f);
    ((float4*)Xo)[i * 32 + fl] = o;
}

// ---------------- Fused mean pool + MLP head ----------------

__global__ __launch_bounds__(256) void k_poolmlp(const float* __restrict__ X, const int* __restrict__ batch,
                                                 const float* __restrict__ w1, const float* __restrict__ b1,
                                                 const float* __restrict__ w2, const float* __restrict__ b2,
                                                 float* __restrict__ out) {
    __shared__ int s_lo, s_hi;
    __shared__ float red[256];
    __shared__ float xs[128];
    __shared__ float hs[256];
    int g = blockIdx.x, tid = threadIdx.x;
    if (tid == 0) {
        int lo = 0, hi = N_NODES;
        while (lo < hi) { int mid = (lo + hi) >> 1; if (batch[mid] < g) lo = mid + 1; else hi = mid; }
        s_lo = lo;
        int lo2 = lo, hi2 = N_NODES;
        while (lo2 < hi2) { int mid = (lo2 + hi2) >> 1; if (batch[mid] < g + 1) lo2 = mid + 1; else hi2 = mid; }
        s_hi = lo2;
    }
    __syncthreads();
    int lo = s_lo, hi = s_hi;
    int f = tid & 127, half = tid >> 7;
    float acc = 0.f;
    for (int r = lo + half; r < hi; r += 2) acc += X[r * 128 + f];
    red[tid] = acc;
    __syncthreads();
    if (tid < 128) {
        int cnt = hi - lo;
        xs[tid] = (red[tid] + red[tid + 128]) / (float)(cnt > 0 ? cnt : 1);
    }
    __syncthreads();
    float a1 = b1[tid];
#pragma unroll 8
    for (int k = 0; k < 128; ++k) a1 += xs[k] * w1[k * H_DIM + tid];
    hs[tid] = fmaxf(a1, 0.f);
    __syncthreads();
    int j = tid >> 7, t2 = tid & 127;
    float p = hs[t2] * w2[t2 * LABEL_DIM + j] + hs[t2 + 128] * w2[(t2 + 128) * LABEL_DIM + j];
    red[tid] = p;
    __syncthreads();
    for (int s2 = 64; s2 > 0; s2 >>= 1) {
        if (t2 < s2) red[tid] += red[tid + s2];
        __syncthreads();
    }
    if (t2 == 0) out[g * LABEL_DIM + j] = red[tid] + b2[j];
}

// ---------------- launch ----------------

extern "C" void kernel_launch(void* const* d_in, const int* in_sizes, int n_in,
                              void* d_out, int out_size, void* d_ws, size_t ws_size,
                              hipStream_t stream) {
    const float* x   = (const float*)d_in[0];
    const float* Wg  = (const float*)d_in[1];
    const float* bg  = (const float*)d_in[2];
    const float* w1  = (const float*)d_in[3];
    const float* b1  = (const float*)d_in[4];
    const float* w2  = (const float*)d_in[5];
    const float* b2  = (const float*)d_in[6];
    const int* eidx  = (const int*)d_in[7];
    const int* batch = (const int*)d_in[8];
    float* out = (float*)d_out;

    const int* src = eidx;
    const int* dst = eidx + N_EDGES;

    char* ws = (char*)d_ws;
    size_t off = 0;
    float* A = (float*)(ws + off); off += (size_t)N_NODES * FEA_DIM * 4;
    float* B = (float*)(ws + off); off += (size_t)N_NODES * FEA_DIM * 4;
    int*   col = (int*)(ws + off); off += (size_t)N_EDGES * 4;
    int*   row_ptr = (int*)(ws + off); off += 200704;
    int*   cursor  = (int*)(ws + off); off += 200704;
    int*   counts  = (int*)(ws + off); off += 200704;
    float* dinv    = (float*)(ws + off); off += 200704;
    int*   partial = (int*)(ws + off); off += 4096;

    hipMemsetAsync(cursor, 0, 2 * 200704, stream);   // zeros cursor + counts
    k_count<<<(N_EDGES + 255) / 256, 256, 0, stream>>>(dst, counts);
    k_partial<<<SCAN_NB, 256, 0, stream>>>(counts, partial);
    k_rowptr<<<SCAN_NB, 256, 0, stream>>>(counts, partial, row_ptr, dinv);
    k_fill<<<(N_EDGES + 255) / 256, 256, 0, stream>>>(src, dst, row_ptr, cursor, col);

    const float* cur = x;
    for (int l = 0; l < N_LAYER; ++l) {
        k_gemm<<<(N_NODES + 127) / 128, 256, 0, stream>>>(cur, Wg + (size_t)l * FEA_DIM * FEA_DIM, B, N_NODES);
        k_agg<<<(N_NODES + 7) / 8, 256, 0, stream>>>(B, bg + (size_t)l * FEA_DIM, row_ptr, col, dinv, A);
        cur = A;
    }
    k_poolmlp<<<N_GRAPHS, 256, 0, stream>>>(A, batch, w1, b1, w2, b2, out);
}

// Round 6
// 409.515 us; speedup vs baseline: 1.3837x; 1.0267x over previous
//
#include <hip/hip_runtime.h>
#include <hip/hip_bf16.h>

#define N_NODES 50000
#define N_EDGES 600000
#define FEA_DIM 128
#define H_DIM 256
#define N_LAYER 3
#define N_GRAPHS 256
#define LABEL_DIM 2

#define SCAN_NB ((N_NODES + 255) / 256)        // 196
#define GEMM_NB ((N_NODES + 127) / 128)        // 391
#define COUNT_NB ((N_EDGES + 255) / 256)       // 2344

// ---------------- GEMM body: H[M,128] = X[M,128] @ W[128,128] (fp32 vector) -------
// BM=128, BN=128, BK=32, 256 threads, 8x8 micro-tile; A staged transposed [k][m].
// k accumulation order ascending 0..127 — bitwise stable across rounds.

__device__ __forceinline__ void gemm_body(const float* __restrict__ X, const float* __restrict__ W,
                                          float* __restrict__ H, int M, int tile) {
    __shared__ float a_s[32][132];
    __shared__ float b_s[32][128];
    const int tid = threadIdx.x;
    const int row_g = tid >> 4;
    const int col_g = tid & 15;
    const int row_base = tile * 128;
    float acc[8][8] = {};

    for (int kt = 0; kt < 4; ++kt) {
        const int k0 = kt * 32;
#pragma unroll
        for (int j = 0; j < 4; ++j) {
            int id = tid + j * 256;
            int m = id >> 3;
            int kq = (id & 7) << 2;
            float4 v = make_float4(0.f, 0.f, 0.f, 0.f);
            int gr = row_base + m;
            if (gr < M) v = *(const float4*)(X + gr * 128 + k0 + kq);
            a_s[kq + 0][m] = v.x; a_s[kq + 1][m] = v.y;
            a_s[kq + 2][m] = v.z; a_s[kq + 3][m] = v.w;
        }
#pragma unroll
        for (int j = 0; j < 4; ++j) {
            int id = tid + j * 256;
            int k = id >> 5;
            int n = (id & 31) << 2;
            *(float4*)(&b_s[k][n]) = *(const float4*)(W + (k0 + k) * 128 + n);
        }
        __syncthreads();
#pragma unroll 8
        for (int k = 0; k < 32; ++k) {
            float4 a0 = *(const float4*)(&a_s[k][row_g * 8]);
            float4 a1 = *(const float4*)(&a_s[k][row_g * 8 + 4]);
            float4 b0 = *(const float4*)(&b_s[k][col_g * 4]);
            float4 b1 = *(const float4*)(&b_s[k][64 + col_g * 4]);
            float av[8] = {a0.x, a0.y, a0.z, a0.w, a1.x, a1.y, a1.z, a1.w};
            float bv[8] = {b0.x, b0.y, b0.z, b0.w, b1.x, b1.y, b1.z, b1.w};
#pragma unroll
            for (int i = 0; i < 8; ++i)
#pragma unroll
                for (int jj = 0; jj < 8; ++jj) acc[i][jj] += av[i] * bv[jj];
        }
        __syncthreads();
    }
#pragma unroll
    for (int i = 0; i < 8; ++i) {
        int gr = row_base + row_g * 8 + i;
        if (gr < M) {
            float4 o0 = {acc[i][0], acc[i][1], acc[i][2], acc[i][3]};
            float4 o1 = {acc[i][4], acc[i][5], acc[i][6], acc[i][7]};
            *(float4*)(H + gr * 128 + col_g * 4) = o0;
            *(float4*)(H + gr * 128 + 64 + col_g * 4) = o1;
        }
    }
}

__global__ __launch_bounds__(256) void k_gemm(const float* __restrict__ X, const float* __restrict__ W,
                                              float* __restrict__ H, int M) {
    gemm_body(X, W, H, M, blockIdx.x);
}

// Fused: blocks [0, GEMM_NB) run GEMM layer-0 tiles; blocks [GEMM_NB, ...) count
// edge in-degrees. The two works are independent (count only needs dst; gemm0
// only needs x, Wg0). Hides the count kernel behind gemm0.
__global__ __launch_bounds__(256) void k_gemm0_count(const float* __restrict__ X, const float* __restrict__ W,
                                                     float* __restrict__ H,
                                                     const int* __restrict__ dst, int* __restrict__ counts) {
    if (blockIdx.x < GEMM_NB) {
        gemm_body(X, W, H, N_NODES, blockIdx.x);
    } else {
        int e = (blockIdx.x - GEMM_NB) * 256 + threadIdx.x;
        if (e < N_EDGES) atomicAdd(&counts[dst[e]], 1);
    }
}

// ---------------- CSR build (scan phases) ----------------

__global__ __launch_bounds__(256) void k_partial(const int* __restrict__ counts, int* __restrict__ partial) {
    int g = blockIdx.x * 256 + threadIdx.x;
    int v = (g < N_NODES) ? counts[g] : 0;
#pragma unroll
    for (int off = 32; off > 0; off >>= 1) v += __shfl_down(v, off);
    __shared__ int ws[4];
    int lane = threadIdx.x & 63, wid = threadIdx.x >> 6;
    if (lane == 0) ws[wid] = v;
    __syncthreads();
    if (threadIdx.x == 0) partial[blockIdx.x] = ws[0] + ws[1] + ws[2] + ws[3];
}

// redundant scan of partials per block + block-local scan; also zeroes cursor.
__global__ __launch_bounds__(256) void k_rowptr(const int* __restrict__ counts, const int* __restrict__ partial,
                                                int* __restrict__ row_ptr, float* __restrict__ dinv,
                                                int* __restrict__ cursor) {
    __shared__ int sp[256];
    __shared__ int s[256];
    int tid = threadIdx.x;
    sp[tid] = (tid < SCAN_NB) ? partial[tid] : 0;
    __syncthreads();
#pragma unroll
    for (int off = 1; off < 256; off <<= 1) {
        int t = (tid >= off) ? sp[tid - off] : 0;
        __syncthreads();
        sp[tid] += t;
        __syncthreads();
    }
    int block_off = (blockIdx.x == 0) ? 0 : sp[blockIdx.x - 1];

    int g = blockIdx.x * 256 + tid;
    int c = (g < N_NODES) ? counts[g] : 0;
    s[tid] = c;
    __syncthreads();
#pragma unroll
    for (int off = 1; off < 256; off <<= 1) {
        int t = (tid >= off) ? s[tid - off] : 0;
        __syncthreads();
        s[tid] += t;
        __syncthreads();
    }
    if (g < N_NODES) {
        row_ptr[g] = block_off + s[tid] - c;            // exclusive
        dinv[g] = rsqrtf((float)c + 1.0f);              // +1 = self loop
        cursor[g] = 0;
    }
    if (blockIdx.x == 0 && tid == 0) row_ptr[N_NODES] = sp[SCAN_NB - 1];
}

__global__ __launch_bounds__(256) void k_fill(const int* __restrict__ src, const int* __restrict__ dst,
                                              const int* __restrict__ row_ptr, int* __restrict__ cursor,
                                              int* __restrict__ col) {
    int e = blockIdx.x * 256 + threadIdx.x;
    if (e >= N_EDGES) return;
    int s = src[e], d = dst[e];
    int p = row_ptr[d] + atomicAdd(&cursor[d], 1);
    col[p] = s;
}

// ---------------- Aggregation v4: software-pipelined gathers ----------------
// Two nodes per wave (half-wave each), lane = float4 of 4 feats. Per output
// element the fmac order is unchanged: self-loop, then edges strictly
// ascending (batches accumulated fully in order). Pipelining: batch j+1's
// gathers are ISSUED before batch j is accumulated, so loads stay in flight
// through the accumulate phase instead of draining vmcnt(0) every 8 edges.

__global__ __launch_bounds__(256) void k_agg(const float* __restrict__ H, const float* __restrict__ bgl,
                                             const int* __restrict__ row_ptr, const int* __restrict__ col,
                                             const float* __restrict__ dinv,
                                             float* __restrict__ Xo) {
    const int i = (blockIdx.x * 256 + threadIdx.x) >> 5;   // node id per half-wave
    if (i >= N_NODES) return;
    const int fl = threadIdx.x & 31;
    const float4* H4 = (const float4*)H;
    const float di = dinv[i];
    float4 h = H4[(size_t)i * 32 + fl];
    const float wself = di * di;
    float4 acc = make_float4(h.x * wself, h.y * wself, h.z * wself, h.w * wself);
    const int p0 = row_ptr[i], p1 = row_ptr[i + 1];
    for (int base = p0; base < p1; base += 32) {
        int m = p1 - base; if (m > 32) m = 32;
        int sc = 0; float wc = 0.f;
        if (fl < m) { sc = col[base + fl]; wc = dinv[sc] * di; }
        float4 hb0[8], hb1[8]; float wb0[8], wb1[8];
        int cnt0 = (m < 8) ? m : 8;
        // preload batch 0
#pragma unroll
        for (int t = 0; t < 8; ++t) {
            if (t < cnt0) {
                int s = __shfl(sc, t, 32);
                wb0[t] = __shfl(wc, t, 32);
                hb0[t] = H4[(size_t)s * 32 + fl];
            }
        }
        for (int j = 8; j < m; j += 8) {
            int cnt1 = m - j; if (cnt1 > 8) cnt1 = 8;
            // issue next batch's gathers FIRST (stay in flight over accumulate)
#pragma unroll
            for (int t = 0; t < 8; ++t) {
                if (t < cnt1) {
                    int s = __shfl(sc, j + t, 32);
                    wb1[t] = __shfl(wc, j + t, 32);
                    hb1[t] = H4[(size_t)s * 32 + fl];
                }
            }
            // accumulate previous batch, strictly ascending
#pragma unroll
            for (int t = 0; t < 8; ++t) {
                if (t < cnt0) {
                    acc.x += hb0[t].x * wb0[t];
                    acc.y += hb0[t].y * wb0[t];
                    acc.z += hb0[t].z * wb0[t];
                    acc.w += hb0[t].w * wb0[t];
                }
            }
#pragma unroll
            for (int t = 0; t < 8; ++t) { hb0[t] = hb1[t]; wb0[t] = wb1[t]; }
            cnt0 = cnt1;
        }
        // tail batch
#pragma unroll
        for (int t = 0; t < 8; ++t) {
            if (t < cnt0) {
                acc.x += hb0[t].x * wb0[t];
                acc.y += hb0[t].y * wb0[t];
                acc.z += hb0[t].z * wb0[t];
                acc.w += hb0[t].w * wb0[t];
            }
        }
    }
    float4 b = ((const float4*)bgl)[fl];
    float4 o;
    o.x = fmaxf(acc.x + b.x, 0.f);
    o.y = fmaxf(acc.y + b.y, 0.f);
    o.z = fmaxf(acc.z + b.z, 0.f);
    o.w = fmaxf(acc.w + b.w, 0.f);
    ((float4*)Xo)[(size_t)i * 32 + fl] = o;
}

// ---------------- Fused mean pool + MLP head ----------------

__global__ __launch_bounds__(256) void k_poolmlp(const float* __restrict__ X, const int* __restrict__ batch,
                                                 const float* __restrict__ w1, const float* __restrict__ b1,
                                                 const float* __restrict__ w2, const float* __restrict__ b2,
                                                 float* __restrict__ out) {
    __shared__ int s_lo, s_hi;
    __shared__ float red[256];
    __shared__ float xs[128];
    __shared__ float hs[256];
    int g = blockIdx.x, tid = threadIdx.x;
    if (tid == 0) {
        int lo = 0, hi = N_NODES;
        while (lo < hi) { int mid = (lo + hi) >> 1; if (batch[mid] < g) lo = mid + 1; else hi = mid; }
        s_lo = lo;
        int lo2 = lo, hi2 = N_NODES;
        while (lo2 < hi2) { int mid = (lo2 + hi2) >> 1; if (batch[mid] < g + 1) lo2 = mid + 1; else hi2 = mid; }
        s_hi = lo2;
    }
    __syncthreads();
    int lo = s_lo, hi = s_hi;
    int f = tid & 127, half = tid >> 7;
    float acc = 0.f;
    for (int r = lo + half; r < hi; r += 2) acc += X[r * 128 + f];
    red[tid] = acc;
    __syncthreads();
    if (tid < 128) {
        int cnt = hi - lo;
        xs[tid] = (red[tid] + red[tid + 128]) / (float)(cnt > 0 ? cnt : 1);
    }
    __syncthreads();
    float a1 = b1[tid];
#pragma unroll 8
    for (int k = 0; k < 128; ++k) a1 += xs[k] * w1[k * H_DIM + tid];
    hs[tid] = fmaxf(a1, 0.f);
    __syncthreads();
    int j = tid >> 7, t2 = tid & 127;
    float p = hs[t2] * w2[t2 * LABEL_DIM + j] + hs[t2 + 128] * w2[(t2 + 128) * LABEL_DIM + j];
    red[tid] = p;
    __syncthreads();
    for (int s2 = 64; s2 > 0; s2 >>= 1) {
        if (t2 < s2) red[tid] += red[tid + s2];
        __syncthreads();
    }
    if (t2 == 0) out[g * LABEL_DIM + j] = red[tid] + b2[j];
}

// ---------------- launch ----------------

extern "C" void kernel_launch(void* const* d_in, const int* in_sizes, int n_in,
                              void* d_out, int out_size, void* d_ws, size_t ws_size,
                              hipStream_t stream) {
    const float* x   = (const float*)d_in[0];
    const float* Wg  = (const float*)d_in[1];
    const float* bg  = (const float*)d_in[2];
    const float* w1  = (const float*)d_in[3];
    const float* b1  = (const float*)d_in[4];
    const float* w2  = (const float*)d_in[5];
    const float* b2  = (const float*)d_in[6];
    const int* eidx  = (const int*)d_in[7];
    const int* batch = (const int*)d_in[8];
    float* out = (float*)d_out;

    const int* src = eidx;
    const int* dst = eidx + N_EDGES;

    char* ws = (char*)d_ws;
    size_t off = 0;
    float* A = (float*)(ws + off); off += (size_t)N_NODES * FEA_DIM * 4;
    float* B = (float*)(ws + off); off += (size_t)N_NODES * FEA_DIM * 4;
    int*   col = (int*)(ws + off); off += (size_t)N_EDGES * 4;
    int*   row_ptr = (int*)(ws + off); off += 200704;
    int*   cursor  = (int*)(ws + off); off += 200704;
    int*   counts  = (int*)(ws + off); off += 200704;
    float* dinv    = (float*)(ws + off); off += 200704;
    int*   partial = (int*)(ws + off); off += 4096;

    hipMemsetAsync(counts, 0, 200704, stream);
    // gemm layer-0 fused with degree counting (independent works)
    k_gemm0_count<<<GEMM_NB + COUNT_NB, 256, 0, stream>>>(x, Wg, B, dst, counts);
    k_partial<<<SCAN_NB, 256, 0, stream>>>(counts, partial);
    k_rowptr<<<SCAN_NB, 256, 0, stream>>>(counts, partial, row_ptr, dinv, cursor);
    k_fill<<<COUNT_NB, 256, 0, stream>>>(src, dst, row_ptr, cursor, col);

    k_agg<<<(N_NODES + 7) / 8, 256, 0, stream>>>(B, bg + 0 * FEA_DIM, row_ptr, col, dinv, A);
    for (int l = 1; l < N_LAYER; ++l) {
        k_gemm<<<GEMM_NB, 256, 0, stream>>>(A, Wg + (size_t)l * FEA_DIM * FEA_DIM, B, N_NODES);
        k_agg<<<(N_NODES + 7) / 8, 256, 0, stream>>>(B, bg + (size_t)l * FEA_DIM, row_ptr, col, dinv, A);
    }
    k_poolmlp<<<N_GRAPHS, 256, 0, stream>>>(A, batch, w1, b1, w2, b2, out);
}

// Round 7
// 388.981 us; speedup vs baseline: 1.4567x; 1.0528x over previous
//
#include <hip/hip_runtime.h>
#include <hip/hip_bf16.h>

#define N_NODES 50000
#define N_EDGES 600000
#define FEA_DIM 128
#define H_DIM 256
#define N_LAYER 3
#define N_GRAPHS 256
#define LABEL_DIM 2

#define SCAN_NB ((N_NODES + 255) / 256)        // 196
#define GEMM_NB ((N_NODES + 63) / 64)          // 782
#define COUNT_NB ((N_EDGES + 255) / 256)       // 2344

// ---------------- GEMM body: H[M,128] = X[M,128] @ W[128,128] (fp32 vector) -------
// BM=64, BN=128, BK=32, 256 threads, 4x8 micro-tile; A staged transposed [k][m].
// 782 blocks -> ~3 blocks/CU (vs 391 @BM=128 -> 1.5/CU, the round-6 starvation).
// Per-output fmac order: k ascending 0..127 — bitwise stable across rounds.

__device__ __forceinline__ void gemm_body(const float* __restrict__ X, const float* __restrict__ W,
                                          float* __restrict__ H, int M, int tile) {
    __shared__ float a_s[32][68];    // [k][m] 8.7 KB
    __shared__ float b_s[32][128];   // [k][n] 16 KB
    const int tid = threadIdx.x;
    const int row_g = tid >> 4;   // 0..15 -> 4 rows each
    const int col_g = tid & 15;   // 0..15 -> cols col_g*4 and 64+col_g*4
    const int row_base = tile * 64;
    float acc[4][8] = {};

    for (int kt = 0; kt < 4; ++kt) {
        const int k0 = kt * 32;
        // A tile: 64 rows x 32 k = 512 float4 -> 2 per thread (transpose to [k][m])
#pragma unroll
        for (int j = 0; j < 2; ++j) {
            int id = tid + j * 256;
            int m = id >> 3;
            int kq = (id & 7) << 2;
            float4 v = make_float4(0.f, 0.f, 0.f, 0.f);
            int gr = row_base + m;
            if (gr < M) v = *(const float4*)(X + gr * 128 + k0 + kq);
            a_s[kq + 0][m] = v.x; a_s[kq + 1][m] = v.y;
            a_s[kq + 2][m] = v.z; a_s[kq + 3][m] = v.w;
        }
        // B tile: 32 k x 128 n = 1024 float4 -> 4 per thread
#pragma unroll
        for (int j = 0; j < 4; ++j) {
            int id = tid + j * 256;
            int k = id >> 5;
            int n = (id & 31) << 2;
            *(float4*)(&b_s[k][n]) = *(const float4*)(W + (k0 + k) * 128 + n);
        }
        __syncthreads();
#pragma unroll 8
        for (int k = 0; k < 32; ++k) {
            float4 a0 = *(const float4*)(&a_s[k][row_g * 4]);
            float4 b0 = *(const float4*)(&b_s[k][col_g * 4]);
            float4 b1 = *(const float4*)(&b_s[k][64 + col_g * 4]);
            float av[4] = {a0.x, a0.y, a0.z, a0.w};
            float bv[8] = {b0.x, b0.y, b0.z, b0.w, b1.x, b1.y, b1.z, b1.w};
#pragma unroll
            for (int i = 0; i < 4; ++i)
#pragma unroll
                for (int jj = 0; jj < 8; ++jj) acc[i][jj] += av[i] * bv[jj];
        }
        __syncthreads();
    }
#pragma unroll
    for (int i = 0; i < 4; ++i) {
        int gr = row_base + row_g * 4 + i;
        if (gr < M) {
            float4 o0 = {acc[i][0], acc[i][1], acc[i][2], acc[i][3]};
            float4 o1 = {acc[i][4], acc[i][5], acc[i][6], acc[i][7]};
            *(float4*)(H + gr * 128 + col_g * 4) = o0;
            *(float4*)(H + gr * 128 + 64 + col_g * 4) = o1;
        }
    }
}

__global__ __launch_bounds__(256) void k_gemm(const float* __restrict__ X, const float* __restrict__ W,
                                              float* __restrict__ H, int M) {
    gemm_body(X, W, H, M, blockIdx.x);
}

// Fused: blocks [0, GEMM_NB) run GEMM layer-0 tiles; blocks [GEMM_NB, ...) count
// edge in-degrees (independent works).
__global__ __launch_bounds__(256) void k_gemm0_count(const float* __restrict__ X, const float* __restrict__ W,
                                                     float* __restrict__ H,
                                                     const int* __restrict__ dst, int* __restrict__ counts) {
    if (blockIdx.x < GEMM_NB) {
        gemm_body(X, W, H, N_NODES, blockIdx.x);
    } else {
        int e = (blockIdx.x - GEMM_NB) * 256 + threadIdx.x;
        if (e < N_EDGES) atomicAdd(&counts[dst[e]], 1);
    }
}

// ---------------- CSR build (scan phases) ----------------

__global__ __launch_bounds__(256) void k_partial(const int* __restrict__ counts, int* __restrict__ partial) {
    int g = blockIdx.x * 256 + threadIdx.x;
    int v = (g < N_NODES) ? counts[g] : 0;
#pragma unroll
    for (int off = 32; off > 0; off >>= 1) v += __shfl_down(v, off);
    __shared__ int ws[4];
    int lane = threadIdx.x & 63, wid = threadIdx.x >> 6;
    if (lane == 0) ws[wid] = v;
    __syncthreads();
    if (threadIdx.x == 0) partial[blockIdx.x] = ws[0] + ws[1] + ws[2] + ws[3];
}

__global__ __launch_bounds__(256) void k_rowptr(const int* __restrict__ counts, const int* __restrict__ partial,
                                                int* __restrict__ row_ptr, float* __restrict__ dinv,
                                                int* __restrict__ cursor) {
    __shared__ int sp[256];
    __shared__ int s[256];
    int tid = threadIdx.x;
    sp[tid] = (tid < SCAN_NB) ? partial[tid] : 0;
    __syncthreads();
#pragma unroll
    for (int off = 1; off < 256; off <<= 1) {
        int t = (tid >= off) ? sp[tid - off] : 0;
        __syncthreads();
        sp[tid] += t;
        __syncthreads();
    }
    int block_off = (blockIdx.x == 0) ? 0 : sp[blockIdx.x - 1];

    int g = blockIdx.x * 256 + tid;
    int c = (g < N_NODES) ? counts[g] : 0;
    s[tid] = c;
    __syncthreads();
#pragma unroll
    for (int off = 1; off < 256; off <<= 1) {
        int t = (tid >= off) ? s[tid - off] : 0;
        __syncthreads();
        s[tid] += t;
        __syncthreads();
    }
    if (g < N_NODES) {
        row_ptr[g] = block_off + s[tid] - c;            // exclusive
        dinv[g] = rsqrtf((float)c + 1.0f);              // +1 = self loop
        cursor[g] = 0;
    }
    if (blockIdx.x == 0 && tid == 0) row_ptr[N_NODES] = sp[SCAN_NB - 1];
}

__global__ __launch_bounds__(256) void k_fill(const int* __restrict__ src, const int* __restrict__ dst,
                                              const int* __restrict__ row_ptr, int* __restrict__ cursor,
                                              int* __restrict__ col) {
    int e = blockIdx.x * 256 + threadIdx.x;
    if (e >= N_EDGES) return;
    int s = src[e], d = dst[e];
    int p = row_ptr[d] + atomicAdd(&cursor[d], 1);
    col[p] = s;
}

// ---------------- Aggregation: software-pipelined gathers ----------------
// Two nodes per wave (half-wave each), lane = float4 of 4 feats. Per-output
// fmac order: self-loop, then edges strictly ascending.

__global__ __launch_bounds__(256) void k_agg(const float* __restrict__ H, const float* __restrict__ bgl,
                                             const int* __restrict__ row_ptr, const int* __restrict__ col,
                                             const float* __restrict__ dinv,
                                             float* __restrict__ Xo) {
    const int i = (blockIdx.x * 256 + threadIdx.x) >> 5;   // node id per half-wave
    if (i >= N_NODES) return;
    const int fl = threadIdx.x & 31;
    const float4* H4 = (const float4*)H;
    const float di = dinv[i];
    float4 h = H4[(size_t)i * 32 + fl];
    const float wself = di * di;
    float4 acc = make_float4(h.x * wself, h.y * wself, h.z * wself, h.w * wself);
    const int p0 = row_ptr[i], p1 = row_ptr[i + 1];
    for (int base = p0; base < p1; base += 32) {
        int m = p1 - base; if (m > 32) m = 32;
        int sc = 0; float wc = 0.f;
        if (fl < m) { sc = col[base + fl]; wc = dinv[sc] * di; }
        float4 hb0[8], hb1[8]; float wb0[8], wb1[8];
        int cnt0 = (m < 8) ? m : 8;
#pragma unroll
        for (int t = 0; t < 8; ++t) {
            if (t < cnt0) {
                int s = __shfl(sc, t, 32);
                wb0[t] = __shfl(wc, t, 32);
                hb0[t] = H4[(size_t)s * 32 + fl];
            }
        }
        for (int j = 8; j < m; j += 8) {
            int cnt1 = m - j; if (cnt1 > 8) cnt1 = 8;
#pragma unroll
            for (int t = 0; t < 8; ++t) {
                if (t < cnt1) {
                    int s = __shfl(sc, j + t, 32);
                    wb1[t] = __shfl(wc, j + t, 32);
                    hb1[t] = H4[(size_t)s * 32 + fl];
                }
            }
#pragma unroll
            for (int t = 0; t < 8; ++t) {
                if (t < cnt0) {
                    acc.x += hb0[t].x * wb0[t];
                    acc.y += hb0[t].y * wb0[t];
                    acc.z += hb0[t].z * wb0[t];
                    acc.w += hb0[t].w * wb0[t];
                }
            }
#pragma unroll
            for (int t = 0; t < 8; ++t) { hb0[t] = hb1[t]; wb0[t] = wb1[t]; }
            cnt0 = cnt1;
        }
#pragma unroll
        for (int t = 0; t < 8; ++t) {
            if (t < cnt0) {
                acc.x += hb0[t].x * wb0[t];
                acc.y += hb0[t].y * wb0[t];
                acc.z += hb0[t].z * wb0[t];
                acc.w += hb0[t].w * wb0[t];
            }
        }
    }
    float4 b = ((const float4*)bgl)[fl];
    float4 o;
    o.x = fmaxf(acc.x + b.x, 0.f);
    o.y = fmaxf(acc.y + b.y, 0.f);
    o.z = fmaxf(acc.z + b.z, 0.f);
    o.w = fmaxf(acc.w + b.w, 0.f);
    ((float4*)Xo)[(size_t)i * 32 + fl] = o;
}

// ---------------- Fused mean pool + MLP head ----------------

__global__ __launch_bounds__(256) void k_poolmlp(const float* __restrict__ X, const int* __restrict__ batch,
                                                 const float* __restrict__ w1, const float* __restrict__ b1,
                                                 const float* __restrict__ w2, const float* __restrict__ b2,
                                                 float* __restrict__ out) {
    __shared__ int s_lo, s_hi;
    __shared__ float red[256];
    __shared__ float xs[128];
    __shared__ float hs[256];
    int g = blockIdx.x, tid = threadIdx.x;
    if (tid == 0) {
        int lo = 0, hi = N_NODES;
        while (lo < hi) { int mid = (lo + hi) >> 1; if (batch[mid] < g) lo = mid + 1; else hi = mid; }
        s_lo = lo;
        int lo2 = lo, hi2 = N_NODES;
        while (lo2 < hi2) { int mid = (lo2 + hi2) >> 1; if (batch[mid] < g + 1) lo2 = mid + 1; else hi2 = mid; }
        s_hi = lo2;
    }
    __syncthreads();
    int lo = s_lo, hi = s_hi;
    int f = tid & 127, half = tid >> 7;
    float acc = 0.f;
    for (int r = lo + half; r < hi; r += 2) acc += X[r * 128 + f];
    red[tid] = acc;
    __syncthreads();
    if (tid < 128) {
        int cnt = hi - lo;
        xs[tid] = (red[tid] + red[tid + 128]) / (float)(cnt > 0 ? cnt : 1);
    }
    __syncthreads();
    float a1 = b1[tid];
#pragma unroll 8
    for (int k = 0; k < 128; ++k) a1 += xs[k] * w1[k * H_DIM + tid];
    hs[tid] = fmaxf(a1, 0.f);
    __syncthreads();
    int j = tid >> 7, t2 = tid & 127;
    float p = hs[t2] * w2[t2 * LABEL_DIM + j] + hs[t2 + 128] * w2[(t2 + 128) * LABEL_DIM + j];
    red[tid] = p;
    __syncthreads();
    for (int s2 = 64; s2 > 0; s2 >>= 1) {
        if (t2 < s2) red[tid] += red[tid + s2];
        __syncthreads();
    }
    if (t2 == 0) out[g * LABEL_DIM + j] = red[tid] + b2[j];
}

// ---------------- launch ----------------

extern "C" void kernel_launch(void* const* d_in, const int* in_sizes, int n_in,
                              void* d_out, int out_size, void* d_ws, size_t ws_size,
                              hipStream_t stream) {
    const float* x   = (const float*)d_in[0];
    const float* Wg  = (const float*)d_in[1];
    const float* bg  = (const float*)d_in[2];
    const float* w1  = (const float*)d_in[3];
    const float* b1  = (const float*)d_in[4];
    const float* w2  = (const float*)d_in[5];
    const float* b2  = (const float*)d_in[6];
    const int* eidx  = (const int*)d_in[7];
    const int* batch = (const int*)d_in[8];
    float* out = (float*)d_out;

    const int* src = eidx;
    const int* dst = eidx + N_EDGES;

    char* ws = (char*)d_ws;
    size_t off = 0;
    float* A = (float*)(ws + off); off += (size_t)N_NODES * FEA_DIM * 4;
    float* B = (float*)(ws + off); off += (size_t)N_NODES * FEA_DIM * 4;
    int*   col = (int*)(ws + off); off += (size_t)N_EDGES * 4;
    int*   row_ptr = (int*)(ws + off); off += 200704;
    int*   cursor  = (int*)(ws + off); off += 200704;
    int*   counts  = (int*)(ws + off); off += 200704;
    float* dinv    = (float*)(ws + off); off += 200704;
    int*   partial = (int*)(ws + off); off += 4096;

    hipMemsetAsync(counts, 0, 200704, stream);
    // gemm layer-0 fused with degree counting (independent works)
    k_gemm0_count<<<GEMM_NB + COUNT_NB, 256, 0, stream>>>(x, Wg, B, dst, counts);
    k_partial<<<SCAN_NB, 256, 0, stream>>>(counts, partial);
    k_rowptr<<<SCAN_NB, 256, 0, stream>>>(counts, partial, row_ptr, dinv, cursor);
    k_fill<<<COUNT_NB, 256, 0, stream>>>(src, dst, row_ptr, cursor, col);

    k_agg<<<(N_NODES + 7) / 8, 256, 0, stream>>>(B, bg + 0 * FEA_DIM, row_ptr, col, dinv, A);
    for (int l = 1; l < N_LAYER; ++l) {
        k_gemm<<<GEMM_NB, 256, 0, stream>>>(A, Wg + (size_t)l * FEA_DIM * FEA_DIM, B, N_NODES);
        k_agg<<<(N_NODES + 7) / 8, 256, 0, stream>>>(B, bg + (size_t)l * FEA_DIM, row_ptr, col, dinv, A);
    }
    k_poolmlp<<<N_GRAPHS, 256, 0, stream>>>(A, batch, w1, b1, w2, b2, out);
}